// Round 6
// baseline (548.456 us; speedup 1.0000x reference)
//
#include <hip/hip_runtime.h>
#include <math.h>

#define LOD 64
#define LSD 128
#define KK 16
#define BB 128
#define TT 96
#define OBSD 128
#define ENC 512
#define CH 128
#define OUTD 64
#define TMP 132   // tm2 row pad

__device__ __forceinline__ float elup1f(float x) {
    return x >= 0.0f ? x + 1.0f : expf(x);
}

// ---------------- prep: band-compress basis (entry e = 14*row + s) ----------------
__global__ void prep_basis(const float* __restrict__ tm11, const float* __restrict__ tm12,
                           const float* __restrict__ tm21, const float* __restrict__ tm22,
                           float* __restrict__ basis) {
    int e = blockIdx.x * blockDim.x + threadIdx.x;
    if (e >= 16 * 128 * 14) return;
    int k = e / (128 * 14);
    int rem = e % (128 * 14);
    int row = rem / 14;
    int s = rem % 14;
    int r = row & 63;
    int half = row >> 6;
    int sub = (s >= 7) ? 1 : 0;
    int ss = s - sub * 7;
    int col = r - 3 + ss;
    float v = 0.0f;
    if (col >= 0 && col < 64) {
        const float* src = half ? (sub ? tm22 : tm21) : (sub ? tm12 : tm11);
        v = src[k * 4096 + r * 64 + col];
    }
    basis[e] = v;
}

// ---------------- encoder (unchanged) ----------------
#define EROWS 16
__global__ __launch_bounds__(256, 2)
void encoder_kernel(const float* __restrict__ obs,
                    const float* __restrict__ enc_W, const float* __restrict__ enc_b,
                    const float* __restrict__ wmean_W, const float* __restrict__ wmean_b,
                    const float* __restrict__ wcov_W, const float* __restrict__ wcov_b,
                    float* __restrict__ wm_out, float* __restrict__ wc_out) {
    __shared__ float obs_s[EROWS][OBSD];
    __shared__ float h_s[EROWS][ENC];
    __shared__ float wm_s[EROWS][LOD];
    __shared__ float norm_s[EROWS];
    int tid = threadIdx.x;
    long row0 = (long)blockIdx.x * EROWS;

    for (int idx = tid; idx < EROWS * OBSD; idx += 256) {
        int r = idx >> 7, c = idx & 127;
        obs_s[r][c] = obs[(row0 + r) * OBSD + c];
    }
    __syncthreads();

    for (int p = 0; p < 2; ++p) {
        int c = tid + p * 256;
        float acc[EROWS];
        #pragma unroll
        for (int r = 0; r < EROWS; ++r) acc[r] = 0.f;
        for (int j = 0; j < OBSD; ++j) {
            float w = enc_W[j * ENC + c];
            #pragma unroll
            for (int r = 0; r < EROWS; ++r) acc[r] += obs_s[r][j] * w;
        }
        float b = enc_b[c];
        #pragma unroll
        for (int r = 0; r < EROWS; ++r) h_s[r][c] = fmaxf(acc[r] + b, 0.f);
    }
    __syncthreads();

    {
        int c = tid & 63, g = tid >> 6;
        const float* W = (g < 2) ? wmean_W : wcov_W;
        int r0 = (g & 1) * 8;
        float acc[8];
        #pragma unroll
        for (int r = 0; r < 8; ++r) acc[r] = 0.f;
        for (int j = 0; j < ENC; ++j) {
            float w = W[j * LOD + c];
            #pragma unroll
            for (int r = 0; r < 8; ++r) acc[r] += h_s[r0 + r][j] * w;
        }
        if (g < 2) {
            float b = wmean_b[c];
            #pragma unroll
            for (int r = 0; r < 8; ++r) wm_s[r0 + r][c] = acc[r] + b;
        } else {
            float b = wcov_b[c];
            #pragma unroll
            for (int r = 0; r < 8; ++r)
                wc_out[(row0 + r0 + r) * LOD + c] = elup1f(acc[r] + b);
        }
    }
    __syncthreads();
    if (tid < EROWS) {
        float ss = 0.f;
        for (int c = 0; c < 64; ++c) { float v = wm_s[tid][c]; ss += v * v; }
        norm_s[tid] = sqrtf(ss);
    }
    __syncthreads();
    for (int idx = tid; idx < EROWS * LOD; idx += 256) {
        int r = idx >> 6, c = idx & 63;
        wm_out[(row0 + r) * LOD + c] = wm_s[r][c] / norm_s[r];
    }
}

// ---------------- scan: 2 independent batches per block (512 thr) ----------------
// half = tid>>8 selects the batch chain; phase code identical to R5 per half.
// 2 chains per SIMD -> latency hiding. wm/wc: 1-step register prefetch from
// global (L2-warm). post staged in dynamic LDS (2 x 48KB), bulk-stored at end.
__global__ __launch_bounds__(512, 1)
void scan_kernel(const float* __restrict__ wm_g, const float* __restrict__ wc_g,
                 const float* __restrict__ cW1, const float* __restrict__ cb1,
                 const float* __restrict__ cW2, const float* __restrict__ cb2,
                 const float* __restrict__ basis, const float* __restrict__ log_tc,
                 float* __restrict__ post_g) {
    extern __shared__ __align__(16) float smem[];   // post: 2 * 12288 floats

    __shared__ __align__(16) float meanQ_raw[2][136];   // [4 pad | 128 | 4 pad]
    __shared__ __align__(16) float hpart_s[2][4][LSD];
    __shared__ __align__(16) float hh_s[2][LSD];
    __shared__ __align__(16) float part_s[2][4][16];
    __shared__ __align__(16) float ck_s[2][16];
    __shared__ float tm2[2][16 * TMP];

    int tid = threadIdx.x;
    int half = tid >> 8;          // which batch chain
    int u = tid & 255;            // thread id within chain
    int b = blockIdx.x * 2 + half;
    int w = u >> 6;               // wave within chain
    int l = tid & 63;             // lane
    int k = l & 15;
    int p = l >> 4;               // 0..3

    float* post_lh = smem + half * (TT * 128);
    float* meanQ = meanQ_raw[half] + 4;

    // --- persistent registers ---
    float br[16][7];              // basis entries e = 7*u + j, all 16 k
    #pragma unroll
    for (int q = 0; q < 16; ++q)
        #pragma unroll
        for (int j = 0; j < 7; ++j)
            br[q][j] = basis[q * 1792 + 7 * u + j];

    float w1a[32], w1b[32];       // cW1[32w+j][l], cW1[32w+j][64+l]
    #pragma unroll
    for (int j = 0; j < 32; ++j) {
        w1a[j] = cW1[(32 * w + j) * 128 + l];
        w1b[j] = cW1[(32 * w + j) * 128 + 64 + l];
    }
    float cb1r = cb1[32 * w + (l & 31)];

    float w2r[8];                 // cW2[32w+8p+v][k]
    #pragma unroll
    for (int v = 0; v < 8; ++v)
        w2r[v] = cW2[(32 * w + 8 * p + v) * 16 + k];
    float cb2r = cb2[k];

    // FG state (wave 0 of each chain): carries in registers, lane l owns row l
    float cuR = 10.f, clR = 10.f, csR = 0.f;
    float tcu_r = elup1f(log_tc[l]);
    float tcl_r = elup1f(log_tc[64 + l]);

    // wm/wc register prefetch (1-step lookahead)
    float wmv_c = 0.f, wcv_c = 0.f;
    if (w == 0) {
        wmv_c = wm_g[(long)b * (TT * 64) + l];
        wcv_c = wc_g[(long)b * (TT * 64) + l];
    }

    // --- init shared mean (+pads) ---
    if (u < 136) meanQ_raw[half][u] = 0.f;
    __syncthreads();

    #pragma clang loop unroll(disable)
    for (int t = 0; t < TT; ++t) {
        // prefetch next step's wm/wc (consumed next iteration)
        float wmv_n = 0.f, wcv_n = 0.f;
        if (w == 0) {
            int tn = (t + 1 < TT) ? (t + 1) : t;
            wmv_n = wm_g[(long)b * (TT * 64) + tn * 64 + l];
            wcv_n = wc_g[(long)b * (TT * 64) + tn * 64 + l];
        }
        // wave-0 prefetch of mean windows for FG
        float muw[7], mlw[7];
        if (w == 0) {
            #pragma unroll
            for (int d = 0; d < 7; ++d) {
                muw[d] = meanQ[l + d - 3];
                mlw[d] = meanQ[64 + l + d - 3];
            }
        }

        // ---- P1: hh partials over j in [32w, 32w+32) for cols l and 64+l ----
        {
            const float4* mq = (const float4*)(meanQ + 32 * w);
            float p0 = 0.f, p1 = 0.f;
            #pragma unroll
            for (int j = 0; j < 8; ++j) {
                float4 m4 = mq[j];
                p0 += m4.x * w1a[4 * j] + m4.y * w1a[4 * j + 1]
                    + m4.z * w1a[4 * j + 2] + m4.w * w1a[4 * j + 3];
                p1 += m4.x * w1b[4 * j] + m4.y * w1b[4 * j + 1]
                    + m4.z * w1b[4 * j + 2] + m4.w * w1b[4 * j + 3];
            }
            hpart_s[half][w][l] = p0;
            hpart_s[half][w][64 + l] = p1;
        }
        __syncthreads();   // BAR A

        // ---- P2: combine hh for wave's 32 cols; L: logit partials ----
        if (l < 32) {
            int c = 32 * w + l;
            float hv = fmaxf(hpart_s[half][0][c] + hpart_s[half][1][c]
                             + hpart_s[half][2][c] + hpart_s[half][3][c] + cb1r, 0.f);
            hh_s[half][c] = hv;
        }
        {
            const float4* hq = (const float4*)(hh_s[half] + 32 * w + 8 * p);
            float4 h0 = hq[0];
            float4 h1 = hq[1];
            float pl = h0.x * w2r[0] + h0.y * w2r[1] + h0.z * w2r[2] + h0.w * w2r[3]
                     + h1.x * w2r[4] + h1.y * w2r[5] + h1.z * w2r[6] + h1.w * w2r[7];
            pl += __shfl_xor(pl, 16, 64);
            pl += __shfl_xor(pl, 32, 64);
            if (l < 16) part_s[half][w][l] = pl + ((w == 0) ? cb2r : 0.f);
        }
        __syncthreads();   // BAR B

        // ---- S (wave 0 of each chain): in-lane softmax ----
        if (w == 0) {
            const float4* pq = (const float4*)part_s[half];   // 16 quads
            float4 e0, e1, e2, e3;
            {
                float4 a = pq[0], bq = pq[4], cq = pq[8], dq = pq[12];
                e0.x = __expf(a.x + bq.x + cq.x + dq.x);
                e0.y = __expf(a.y + bq.y + cq.y + dq.y);
                e0.z = __expf(a.z + bq.z + cq.z + dq.z);
                e0.w = __expf(a.w + bq.w + cq.w + dq.w);
            }
            {
                float4 a = pq[1], bq = pq[5], cq = pq[9], dq = pq[13];
                e1.x = __expf(a.x + bq.x + cq.x + dq.x);
                e1.y = __expf(a.y + bq.y + cq.y + dq.y);
                e1.z = __expf(a.z + bq.z + cq.z + dq.z);
                e1.w = __expf(a.w + bq.w + cq.w + dq.w);
            }
            {
                float4 a = pq[2], bq = pq[6], cq = pq[10], dq = pq[14];
                e2.x = __expf(a.x + bq.x + cq.x + dq.x);
                e2.y = __expf(a.y + bq.y + cq.y + dq.y);
                e2.z = __expf(a.z + bq.z + cq.z + dq.z);
                e2.w = __expf(a.w + bq.w + cq.w + dq.w);
            }
            {
                float4 a = pq[3], bq = pq[7], cq = pq[11], dq = pq[15];
                e3.x = __expf(a.x + bq.x + cq.x + dq.x);
                e3.y = __expf(a.y + bq.y + cq.y + dq.y);
                e3.z = __expf(a.z + bq.z + cq.z + dq.z);
                e3.w = __expf(a.w + bq.w + cq.w + dq.w);
            }
            float sm = (e0.x + e0.y + e0.z + e0.w) + (e1.x + e1.y + e1.z + e1.w)
                     + (e2.x + e2.y + e2.z + e2.w) + (e3.x + e3.y + e3.z + e3.w);
            float inv = 1.f / sm;
            e0.x *= inv; e0.y *= inv; e0.z *= inv; e0.w *= inv;
            e1.x *= inv; e1.y *= inv; e1.z *= inv; e1.w *= inv;
            e2.x *= inv; e2.y *= inv; e2.z *= inv; e2.w *= inv;
            e3.x *= inv; e3.y *= inv; e3.z *= inv; e3.w *= inv;
            if (l == 0)      *(float4*)(ck_s[half] + 0)  = e0;
            else if (l == 1) *(float4*)(ck_s[half] + 4)  = e1;
            else if (l == 2) *(float4*)(ck_s[half] + 8)  = e2;
            else if (l == 3) *(float4*)(ck_s[half] + 12) = e3;
        }
        __syncthreads();   // BAR C

        // ---- T: banded Tm entries (7 contiguous per thread) ----
        {
            float4 c0 = *(const float4*)(ck_s[half] + 0);
            float4 c1 = *(const float4*)(ck_s[half] + 4);
            float4 c2 = *(const float4*)(ck_s[half] + 8);
            float4 c3 = *(const float4*)(ck_s[half] + 12);
            int r = u >> 1;
            int s0 = (u & 1) * 7;
            #pragma unroll
            for (int j = 0; j < 7; ++j) {
                float acc = c0.x * br[0][j] + c0.y * br[1][j] + c0.z * br[2][j] + c0.w * br[3][j]
                          + c1.x * br[4][j] + c1.y * br[5][j] + c1.z * br[6][j] + c1.w * br[7][j]
                          + c2.x * br[8][j] + c2.y * br[9][j] + c2.z * br[10][j] + c2.w * br[11][j]
                          + c3.x * br[12][j] + c3.y * br[13][j] + c3.z * br[14][j] + c3.w * br[15][j];
                tm2[half][(s0 + j) * TMP + r] = acc;
            }
        }
        __syncthreads();   // BAR D

        // ---- FG (wave 0 of each chain): banded propagation + Kalman ----
        if (w == 0) {
            int i = l;
            float cun[7], csn[7], cln[7];
            #pragma unroll
            for (int d = 0; d < 7; ++d) {
                int src = i + d - 3;
                cun[d] = __shfl(cuR, src, 64);
                csn[d] = __shfl(csR, src, 64);
                cln[d] = __shfl(clR, src, 64);
            }
            float ua[7], ub[7], la[7], lb[7];
            #pragma unroll
            for (int s = 0; s < 7; ++s) {
                ua[s] = tm2[half][s * TMP + i];
                ub[s] = tm2[half][(7 + s) * TMP + i];
                la[s] = tm2[half][s * TMP + 64 + i];
                lb[s] = tm2[half][(7 + s) * TMP + 64 + i];
            }
            float ncu = tcu_r, ncl = tcl_r, ncs = 0.f, au = 0.f, al = 0.f;
            #pragma unroll
            for (int s = 0; s < 7; ++s) {
                float A = ua[s], Bv = ub[s], C = la[s], D = lb[s];
                float cu = cun[s], cs = csn[s], cl = cln[s];
                ncu += A * A * cu + 2.f * A * Bv * cs + Bv * Bv * cl;
                ncl += C * C * cu + 2.f * C * D * cs + D * D * cl;
                ncs += C * A * cu + (D * A + C * Bv) * cs + D * Bv * cl;
                au += A * muw[s] + Bv * mlw[s];
                al += C * muw[s] + D * mlw[s];
            }
            float denom = ncu + wcv_c;
            float inv = 1.f / denom;
            float qu = ncu * inv, ql = ncs * inv;
            float res = wmv_c - au;
            float pmu = au + qu * res;
            float pml = al + ql * res;
            float cf = 1.f - qu;
            cuR = cf * ncu;
            clR = ncl - ql * ncs;
            csR = cf * ncs;
            meanQ[i] = pmu;
            meanQ[64 + i] = pml;
            post_lh[t * 128 + i] = pmu;
            post_lh[t * 128 + 64 + i] = pml;
        }
        __syncthreads();   // BAR E
        wmv_c = wmv_n;
        wcv_c = wcv_n;
    }

    // --- bulk-store post (each chain's 256 threads) ---
    {
        const float4* s0 = (const float4*)post_lh;
        float4* d0 = (float4*)(post_g + (long)b * (TT * 128));
        for (int idx = u; idx < TT * 128 / 4; idx += 256)
            d0[idx] = s0[idx];
    }
}

// ---------------- decoder (unchanged) ----------------
#define DROWS 16
__global__ __launch_bounds__(256, 2)
void decoder_kernel(const float* __restrict__ post,
                    const float* __restrict__ dec_W, const float* __restrict__ dec_b,
                    const float* __restrict__ varh_W, const float* __restrict__ varh_b,
                    const float* __restrict__ var_W, const float* __restrict__ var_b,
                    float* __restrict__ out) {
    __shared__ float post_s[DROWS][LSD];
    __shared__ float vh_s[DROWS][CH];
    int tid = threadIdx.x;
    long row0 = (long)blockIdx.x * DROWS;
    for (int idx = tid; idx < DROWS * LSD; idx += 256) {
        int r = idx >> 7, c = idx & 127;
        post_s[r][c] = post[(row0 + r) * LSD + c];
    }
    __syncthreads();
    {
        int c = tid & 127, rh = tid >> 7;
        int r0 = rh * 8;
        float acc[8];
        #pragma unroll
        for (int r = 0; r < 8; ++r) acc[r] = 0.f;
        for (int j = 0; j < LSD; ++j) {
            float w = varh_W[j * CH + c];
            #pragma unroll
            for (int r = 0; r < 8; ++r) acc[r] += post_s[r0 + r][j] * w;
        }
        float bb = varh_b[c];
        #pragma unroll
        for (int r = 0; r < 8; ++r) vh_s[r0 + r][c] = fmaxf(acc[r] + bb, 0.f);
    }
    {
        int c = tid & 63, g = tid >> 6;
        int r0 = g * 4;
        float acc[4];
        #pragma unroll
        for (int r = 0; r < 4; ++r) acc[r] = 0.f;
        for (int j = 0; j < LSD; ++j) {
            float w = dec_W[j * OUTD + c];
            #pragma unroll
            for (int r = 0; r < 4; ++r) acc[r] += post_s[r0 + r][j] * w;
        }
        float bb = dec_b[c];
        #pragma unroll
        for (int r = 0; r < 4; ++r) out[(row0 + r0 + r) * 128 + c] = acc[r] + bb;
    }
    __syncthreads();
    {
        int c = tid & 63, g = tid >> 6;
        int r0 = g * 4;
        float acc[4];
        #pragma unroll
        for (int r = 0; r < 4; ++r) acc[r] = 0.f;
        for (int j = 0; j < CH; ++j) {
            float w = var_W[j * OUTD + c];
            #pragma unroll
            for (int r = 0; r < 4; ++r) acc[r] += vh_s[r0 + r][j] * w;
        }
        float bb = var_b[c];
        #pragma unroll
        for (int r = 0; r < 4; ++r) out[(row0 + r0 + r) * 128 + 64 + c] = elup1f(acc[r] + bb);
    }
}

extern "C" void kernel_launch(void* const* d_in, const int* in_sizes, int n_in,
                              void* d_out, int out_size, void* d_ws, size_t ws_size,
                              hipStream_t stream) {
    const float* obs     = (const float*)d_in[0];
    const float* enc_W   = (const float*)d_in[1];
    const float* enc_b   = (const float*)d_in[2];
    const float* wmean_W = (const float*)d_in[3];
    const float* wmean_b = (const float*)d_in[4];
    const float* wcov_W  = (const float*)d_in[5];
    const float* wcov_b  = (const float*)d_in[6];
    const float* cW1     = (const float*)d_in[7];
    const float* cb1     = (const float*)d_in[8];
    const float* cW2     = (const float*)d_in[9];
    const float* cb2     = (const float*)d_in[10];
    const float* tm11    = (const float*)d_in[11];
    const float* tm12    = (const float*)d_in[12];
    const float* tm21    = (const float*)d_in[13];
    const float* tm22    = (const float*)d_in[14];
    const float* log_tc  = (const float*)d_in[15];
    const float* dec_W   = (const float*)d_in[16];
    const float* dec_b   = (const float*)d_in[17];
    const float* varh_W  = (const float*)d_in[18];
    const float* varh_b  = (const float*)d_in[19];
    const float* var_W   = (const float*)d_in[20];
    const float* var_b   = (const float*)d_in[21];

    float* out = (float*)d_out;
    float* ws = (float*)d_ws;
    float* wm_ws    = ws;                 // 12288*64
    float* wc_ws    = ws + 786432;        // 12288*64
    float* post_ws  = ws + 1572864;       // 12288*128
    float* basis_ws = ws + 3145728;       // 16*128*14

    size_t dyn = (size_t)(2 * TT * 128) * sizeof(float);  // 98304 B (post x2)
    (void)hipFuncSetAttribute((const void*)scan_kernel,
                              hipFuncAttributeMaxDynamicSharedMemorySize,
                              (int)dyn);

    prep_basis<<<112, 256, 0, stream>>>(tm11, tm12, tm21, tm22, basis_ws);
    encoder_kernel<<<768, 256, 0, stream>>>(obs, enc_W, enc_b, wmean_W, wmean_b,
                                            wcov_W, wcov_b, wm_ws, wc_ws);
    scan_kernel<<<64, 512, dyn, stream>>>(wm_ws, wc_ws, cW1, cb1, cW2, cb2,
                                          basis_ws, log_tc, post_ws);
    decoder_kernel<<<768, 256, 0, stream>>>(post_ws, dec_W, dec_b, varh_W, varh_b,
                                            var_W, var_b, out);
}